// Round 3
// baseline (278.021 us; speedup 1.0000x reference)
//
#include <hip/hip_runtime.h>

typedef __attribute__((ext_vector_type(8))) short bhalf8;
typedef __attribute__((ext_vector_type(4))) float floatx4;

#define ALPHA_LR 0.2f

__device__ __forceinline__ unsigned short f2bf(float f) {
  union { float f; unsigned int u; } v; v.f = f;
  unsigned int r = v.u + 0x7fffu + ((v.u >> 16) & 1u);
  return (unsigned short)(r >> 16);
}
__device__ __forceinline__ float bf2f(unsigned short u) {
  union { unsigned int u; float f; } v; v.u = ((unsigned int)u) << 16;
  return v.f;
}
// async global->LDS, 16B per lane; LDS dest is wave-uniform base + lane*16
__device__ __forceinline__ void gld16(const void* g, void* l) {
  __builtin_amdgcn_global_load_lds((const __attribute__((address_space(1))) unsigned int*)g,
                                   (__attribute__((address_space(3))) unsigned int*)l,
                                   16, 0, 0);
}

// ---------------------------------------------------------------------------
// k0w: W [k][n] fp32 -> WT_hi/WT_lo bf16, k-tiled layout [ks=8][n=256][k'=32].
// Also re-initializes s2maxEnc[8] (ws is re-poisoned before every call).
// ---------------------------------------------------------------------------
__global__ void k0w_split(const float* __restrict__ W,
                          unsigned short* __restrict__ WThi,
                          unsigned short* __restrict__ WTlo,
                          unsigned int* __restrict__ s2maxEnc) {
  __shared__ float s[16][17];
  const int tx = threadIdx.x, ty = threadIdx.y;
  if (blockIdx.x == 0 && blockIdx.y == 0 && ty == 0 && tx < 8) s2maxEnc[tx] = 0u;
  const int n0 = blockIdx.x * 16, k0 = blockIdx.y * 16;
  s[ty][tx] = W[(k0 + ty) * 256 + n0 + tx];
  __syncthreads();
  float v = s[tx][ty];  // = W[k0+tx][n0+ty]
  const int k = k0 + tx, n = n0 + ty;
  unsigned short hi = f2bf(v);
  unsigned short lo = f2bf(v - bf2f(hi));
  const int idx = (k >> 5) * 8192 + n * 32 + (k & 31);
  WThi[idx] = hi;
  WTlo[idx] = lo;
}

// ---------------------------------------------------------------------------
// k1: Wh = h @ W via split-bf16 MFMA (hi*hi + hi*lo + lo*hi), h split in-kernel.
// Writes WhPack bf16 [B][jt=64][f=256][j'=32], s1/s2 (fp32 dots with a), and
// per-batch encoded atomicMax of s2 (for the k3 softmax bound).
// ---------------------------------------------------------------------------
__global__ __launch_bounds__(512, 2) void k1_mfma(const float* __restrict__ h,
                                                  const unsigned short* __restrict__ Bhi_g,
                                                  const unsigned short* __restrict__ Blo_g,
                                                  const float* __restrict__ a_g,
                                                  unsigned short* __restrict__ WhPack,
                                                  float* __restrict__ s1,
                                                  float* __restrict__ s2,
                                                  unsigned int* __restrict__ s2maxEnc) {
  __shared__ unsigned short Ah[64 * 264], Al[64 * 264];  // 33 KB each
  __shared__ unsigned short Bh[2][8192], Bl[2][8192];    // 16 KB per buffer
  __shared__ float s1red[64], s2red[64];
  const int t = threadIdx.x;
  const long r0 = (long)blockIdx.x * 64;
  const int wave = t >> 6, lane = t & 63;

  if (t < 64) { s1red[t] = 0.f; s2red[t] = 0.f; }

#pragma unroll
  for (int rep = 0; rep < 2; rep++) {
    const int off = wave * 1024 + rep * 512;
    gld16(Bhi_g + off + lane * 8, &Bh[0][off]);
    gld16(Blo_g + off + lane * 8, &Bl[0][off]);
  }

#pragma unroll
  for (int q = 0; q < 8; q++) {
    int idx = q * 512 + t;
    int row = idx >> 6, c4 = idx & 63;
    float4 x = *(const float4*)(h + (r0 + row) * 256 + c4 * 4);
    float xs[4] = {x.x, x.y, x.z, x.w};
    unsigned short hs[4], ls[4];
#pragma unroll
    for (int qq = 0; qq < 4; qq++) {
      hs[qq] = f2bf(xs[qq]);
      ls[qq] = f2bf(xs[qq] - bf2f(hs[qq]));
    }
    *(ushort4*)&Ah[row * 264 + c4 * 4] = (ushort4){hs[0], hs[1], hs[2], hs[3]};
    *(ushort4*)&Al[row * 264 + c4 * 4] = (ushort4){ls[0], ls[1], ls[2], ls[3]};
  }
  __syncthreads();

  const int wm = wave >> 2, wn = wave & 3;
  const int lhi = lane >> 4, llo = lane & 15;

  floatx4 acc[2][4];
#pragma unroll
  for (int mt = 0; mt < 2; mt++)
#pragma unroll
    for (int nt = 0; nt < 4; nt++) acc[mt][nt] = (floatx4){0.f, 0.f, 0.f, 0.f};

  for (int ks = 0; ks < 8; ks++) {
    const int cur = ks & 1, nxt = cur ^ 1, ksn = (ks + 1) & 7;
#pragma unroll
    for (int rep = 0; rep < 2; rep++) {
      const int off = wave * 1024 + rep * 512;
      gld16(Bhi_g + ksn * 8192 + off + lane * 8, &Bh[nxt][off]);
      gld16(Blo_g + ksn * 8192 + off + lane * 8, &Bl[nxt][off]);
    }

    const int k0 = ks * 32;
    bhalf8 ah[2], al[2], bh[4], bl[4];
#pragma unroll
    for (int mt = 0; mt < 2; mt++) {
      int ro = (wm * 32 + mt * 16 + llo) * 264 + k0 + lhi * 8;
      ah[mt] = *(const bhalf8*)&Ah[ro];
      al[mt] = *(const bhalf8*)&Al[ro];
    }
#pragma unroll
    for (int nt = 0; nt < 4; nt++) {
      int ro = (wn * 64 + nt * 16 + llo) * 32 + lhi * 8;
      bh[nt] = *(const bhalf8*)&Bh[cur][ro];
      bl[nt] = *(const bhalf8*)&Bl[cur][ro];
    }
#pragma unroll
    for (int mt = 0; mt < 2; mt++)
#pragma unroll
      for (int nt = 0; nt < 4; nt++) {
        acc[mt][nt] = __builtin_amdgcn_mfma_f32_16x16x32_bf16(ah[mt], bh[nt], acc[mt][nt], 0, 0, 0);
        acc[mt][nt] = __builtin_amdgcn_mfma_f32_16x16x32_bf16(ah[mt], bl[nt], acc[mt][nt], 0, 0, 0);
        acc[mt][nt] = __builtin_amdgcn_mfma_f32_16x16x32_bf16(al[mt], bh[nt], acc[mt][nt], 0, 0, 0);
      }
    __syncthreads();
  }

  float a1v[4], a2v[4];
#pragma unroll
  for (int nt = 0; nt < 4; nt++) {
    int f = wn * 64 + nt * 16 + llo;
    a1v[nt] = a_g[f];
    a2v[nt] = a_g[256 + f];
  }

  const int b = (int)(r0 >> 11);
  const int jt_base = (int)((r0 & 2047) >> 5);

#pragma unroll
  for (int mt = 0; mt < 2; mt++) {
    float p1[4], p2[4];
#pragma unroll
    for (int reg = 0; reg < 4; reg++) {
      p1[reg] = acc[mt][0][reg] * a1v[0] + acc[mt][1][reg] * a1v[1] +
                acc[mt][2][reg] * a1v[2] + acc[mt][3][reg] * a1v[3];
      p2[reg] = acc[mt][0][reg] * a2v[0] + acc[mt][1][reg] * a2v[1] +
                acc[mt][2][reg] * a2v[2] + acc[mt][3][reg] * a2v[3];
    }
#pragma unroll
    for (int off = 1; off < 16; off <<= 1) {
#pragma unroll
      for (int reg = 0; reg < 4; reg++) {
        p1[reg] += __shfl_xor(p1[reg], off);
        p2[reg] += __shfl_xor(p2[reg], off);
      }
    }
    if (llo == 0) {
#pragma unroll
      for (int reg = 0; reg < 4; reg++) {
        int il = wm * 32 + mt * 16 + lhi * 4 + reg;
        atomicAdd(&s1red[il], p1[reg]);
        atomicAdd(&s2red[il], p2[reg]);
      }
    }
#pragma unroll
    for (int nt = 0; nt < 4; nt++) {
      int f = wn * 64 + nt * 16 + llo;
      int jt = jt_base + wm;
      ushort4 pk = (ushort4){f2bf(acc[mt][nt][0]), f2bf(acc[mt][nt][1]),
                             f2bf(acc[mt][nt][2]), f2bf(acc[mt][nt][3])};
      *(ushort4*)&WhPack[((long)((b * 64 + jt) * 256 + f)) * 32 + mt * 16 + lhi * 4] = pk;
    }
  }

  __syncthreads();
  if (t < 64) {
    s1[r0 + t] = s1red[t];
    s2[r0 + t] = s2red[t];
    // per-batch max(s2): 64-lane reduce + one encoded atomicMax per block
    float v = s2red[t];
#pragma unroll
    for (int o = 32; o; o >>= 1) v = fmaxf(v, __shfl_xor(v, o));
    if (t == 0) {
      unsigned int u = __float_as_uint(v);
      unsigned int key = (u & 0x80000000u) ? ~u : (u | 0x80000000u);
      atomicMax(s2maxEnc + b, key);
    }
  }
}

// ---------------------------------------------------------------------------
// K3 v4 (barrier-free, in-register P): out = elu(softmax(mask(leaky(s1+s2)))@Wh)
// Insight: P_ij = adj_ij ? exp(leaky(s1_i+s2_j)-Mi) : 0 needs NO cross-thread
// data: the MFMA A-frag layout (row=lane&15, k=(lane>>4)*8+e) means each lane
// computes its own 8 consecutive-j P values from adj (dense int4x2, coalesced
// across lhi) + s2 (L1 broadcast). So: ZERO LDS, ZERO barriers, no P staging.
// Block = 64 rows x 256 f (8 waves); wave (rg,fg) owns 32 rows x 64 f.
// - exp/adj recomputed 4x across fg waves (same CU -> adj deduped by L1);
//   Wh L2 traffic = 32 blocks/batch x 1 MB = 32 MB/XCD (was 64).
// - adj/Wh/s2 register-prefetched one jt ahead: a full iteration (~350 cyc) of
//   independent VALU+MFMA in flight covers L2/HBM latency; waves never sync.
// grid 256 x 512 thr (1 block/CU, all resident); XCD-affine b = lin&7.
// ---------------------------------------------------------------------------
__global__ __launch_bounds__(512, 2) void k3_attn(const unsigned short* __restrict__ WhPack,
                                                  const int* __restrict__ adj,
                                                  const float* __restrict__ s1g,
                                                  const float* __restrict__ s2g,
                                                  const unsigned int* __restrict__ s2maxEnc,
                                                  float* __restrict__ out) {
  const int t = threadIdx.x;
  const int lin = blockIdx.x;
  const int b = lin & 7;  // XCD-affine: round-robin dispatch -> XCD = lin%8
  const int ig = lin >> 3;
  const int wave = t >> 6, lane = t & 63;
  const int rg = wave >> 2, fg = wave & 3;
  const int i0 = ig * 64 + rg * 32;
  const long gr0 = (long)b * 2048 + i0;
  const int llo = lane & 15, lhi = lane >> 4;

  const unsigned int ek = s2maxEnc[b];
  const float s2max = (ek & 0x80000000u) ? __uint_as_float(ek & 0x7fffffffu)
                                         : __uint_as_float(~ek);
  float s1i[2], Mi[2];
#pragma unroll
  for (int mt = 0; mt < 2; mt++) {
    s1i[mt] = s1g[gr0 + mt * 16 + llo];
    float xm = s1i[mt] + s2max;
    Mi[mt] = fmaxf(xm, ALPHA_LR * xm);
  }

  const float* s2p = s2g + (long)b * 2048 + lhi * 8;  // + jt*32
  const int* ap0 = adj + (gr0 + llo) * 2048 + lhi * 8;
  const int* ap1 = ap0 + 16 * 2048;
  const unsigned short* wb =
      WhPack + (long)b * 524288 + (long)((fg * 64 + llo) * 32 + lhi * 8);

  // prologue: jt=0 operands into regs
  int4 ajA0 = *(const int4*)ap0, ajB0 = *(const int4*)(ap0 + 4);
  int4 ajA1 = *(const int4*)ap1, ajB1 = *(const int4*)(ap1 + 4);
  float4 s2A = *(const float4*)s2p;
  float4 s2B = *(const float4*)(s2p + 4);
  bhalf8 bF[4];
#pragma unroll
  for (int nt = 0; nt < 4; nt++) bF[nt] = *(const bhalf8*)(wb + nt * 512);

  floatx4 acc[2][4];
#pragma unroll
  for (int mt = 0; mt < 2; mt++)
#pragma unroll
    for (int nt = 0; nt < 4; nt++) acc[mt][nt] = (floatx4){0.f, 0.f, 0.f, 0.f};
  float ls0 = 0.f, ls1 = 0.f;

  for (int jt = 0; jt < 64; jt++) {
    const int jn = (jt < 63) ? jt + 1 : 63;
    // ---- prefetch next-iteration operands (fire-and-forget, consumed next jt)
    int4 anA0 = *(const int4*)(ap0 + jn * 32);
    int4 anB0 = *(const int4*)(ap0 + jn * 32 + 4);
    int4 anA1 = *(const int4*)(ap1 + jn * 32);
    int4 anB1 = *(const int4*)(ap1 + jn * 32 + 4);
    float4 s2nA = *(const float4*)(s2p + jn * 32);
    float4 s2nB = *(const float4*)(s2p + jn * 32 + 4);
    bhalf8 bFn[4];
#pragma unroll
    for (int nt = 0; nt < 4; nt++)
      bFn[nt] = *(const bhalf8*)(wb + (long)jn * 8192 + nt * 512);

    // ---- P fragments for current jt, fully in-register
    bhalf8 pa[2];
#pragma unroll
    for (int mt = 0; mt < 2; mt++) {
      const float s1v = s1i[mt], miv = Mi[mt];
      const int4 aA = mt ? ajA1 : ajA0;
      const int4 aB = mt ? ajB1 : ajB0;
      float xs[8] = {s2A.x, s2A.y, s2A.z, s2A.w, s2B.x, s2B.y, s2B.z, s2B.w};
      int am[8] = {aA.x, aA.y, aA.z, aA.w, aB.x, aB.y, aB.z, aB.w};
      float e[8];
      float lsm = 0.f;
#pragma unroll
      for (int q = 0; q < 8; q++) {
        float x = s1v + xs[q];
        float lk = fmaxf(x, ALPHA_LR * x);
        float ee = __expf(lk - miv);
        ee = (am[q] > 0) ? ee : 0.f;
        lsm += ee;
        e[q] = ee;
      }
      if (mt) ls1 += lsm; else ls0 += lsm;
      union { unsigned int u[4]; bhalf8 v; } pk;
#pragma unroll
      for (int q = 0; q < 4; q++)
        asm("v_cvt_pk_bf16_f32 %0, %1, %2" : "=v"(pk.u[q]) : "v"(e[2 * q]), "v"(e[2 * q + 1]));
      pa[mt] = pk.v;
    }

    // ---- MFMA on current operands
#pragma unroll
    for (int mt = 0; mt < 2; mt++)
#pragma unroll
      for (int nt = 0; nt < 4; nt++)
        acc[mt][nt] = __builtin_amdgcn_mfma_f32_16x16x32_bf16(mt ? pa[1] : pa[0],
                                                              bF[nt], acc[mt][nt], 0, 0, 0);

    // ---- rotate prefetched -> current
    ajA0 = anA0; ajB0 = anB0; ajA1 = anA1; ajB1 = anB1;
    s2A = s2nA; s2B = s2nB;
#pragma unroll
    for (int nt = 0; nt < 4; nt++) bF[nt] = bFn[nt];
  }

  // denominator: rows mt*16+llo; partial over lhi j-slices -> reduce across lhi
  ls0 += __shfl_xor(ls0, 16); ls0 += __shfl_xor(ls0, 32);
  ls1 += __shfl_xor(ls1, 16); ls1 += __shfl_xor(ls1, 32);
  float inv0 = 1.f / fmaxf(ls0, 1e-35f);
  float inv1 = 1.f / fmaxf(ls1, 1e-35f);

  // epilogue: normalize, ELU, store. C/D: row = lhi*4+reg, col = llo.
  // inv for row r lives in lanes with llo==r -> fetch via shfl from lane r.
#pragma unroll
  for (int mt = 0; mt < 2; mt++) {
#pragma unroll
    for (int reg = 0; reg < 4; reg++) {
      const int rloc = lhi * 4 + reg;
      float iv = __shfl(mt ? inv1 : inv0, rloc);
      const long orow = (gr0 + mt * 16 + rloc) * 256 + fg * 64 + llo;
#pragma unroll
      for (int nt = 0; nt < 4; nt++) {
        float v = acc[mt][nt][reg] * iv;
        v = v > 0.f ? v : expm1f(v);
        out[orow + nt * 16] = v;
      }
    }
  }
}

// ---------------------------------------------------------------------------
extern "C" void kernel_launch(void* const* d_in, const int* in_sizes, int n_in,
                              void* d_out, int out_size, void* d_ws, size_t ws_size,
                              hipStream_t stream) {
  const float* h = (const float*)d_in[0];
  const int* adj = (const int*)d_in[1];
  const float* W = (const float*)d_in[2];
  const float* a = (const float*)d_in[3];
  float* out = (float*)d_out;

  char* ws = (char*)d_ws;
  unsigned short* WhPack = (unsigned short*)ws;            //  8,388,608 B
  unsigned short* WThi = (unsigned short*)(ws + 8388608);  //    131,072 B
  unsigned short* WTlo = (unsigned short*)(ws + 8519680);  //    131,072 B
  float* s1 = (float*)(ws + 8650752);                      //     65,536 B
  float* s2 = (float*)(ws + 8716288);                      //     65,536 B
  unsigned int* s2maxEnc = (unsigned int*)(ws + 8781824);  //         32 B

  hipLaunchKernelGGL(k0w_split, dim3(16, 16), dim3(16, 16), 0, stream, W, WThi, WTlo, s2maxEnc);
  hipLaunchKernelGGL(k1_mfma, dim3(256), dim3(512), 0, stream, h, WThi, WTlo, a,
                     WhPack, s1, s2, s2maxEnc);
  hipLaunchKernelGGL(k3_attn, dim3(256), dim3(512), 0, stream, WhPack, adj,
                     s1, s2, s2maxEnc, out);
}